// Round 13
// baseline (242.085 us; speedup 1.0000x reference)
//
#include <hip/hip_runtime.h>
#include <hip/hip_bf16.h>

#define NN 8192
#define ND 128
#define BSZ 4096
#define CTX1 32
#define SRC 4096
#define TOPK 8
#define DROPC 5

#define BM 16          // rows per big_gemm block
#define BKC 256        // K floats per macro-step (1KB per row)
#define NMS (NN / BKC) // 32 macro-steps

using f4 = __attribute__((ext_vector_type(4))) float;
using s4 = __attribute__((ext_vector_type(4))) short;
using bfrag = __attribute__((ext_vector_type(8))) short;

__device__ __forceinline__ short f2bf(float x) {
  __hip_bfloat16 h = __float2bfloat16(x);
  return __builtin_bit_cast(short, h);
}
__device__ __forceinline__ float bf2f(short s) {
  unsigned u = ((unsigned)(unsigned short)s) << 16;
  return __builtin_bit_cast(float, u);
}

// ---------------- prep: tfn, wsum, meanpara, lin_W / qkv / translate_W packs ----
__global__ __launch_bounds__(256) void prep_kernel(
    const float* __restrict__ trainfeature, const float* __restrict__ bsnf,
    const float* __restrict__ para, const float* __restrict__ lin_W,
    const float* __restrict__ Wq, const float* __restrict__ Wk,
    const float* __restrict__ Wv, const float* __restrict__ translate_W,
    float* __restrict__ tfn, float* __restrict__ wsum,
    float* __restrict__ meanpara, short* __restrict__ linWp,
    short* __restrict__ qkvWp, short* __restrict__ twP) {
  int blk = blockIdx.x;
  int t = threadIdx.x;
  if (blk < 2048) {                      // tfn: 4 rows per block, one wave per row
    int row = blk * 4 + (t >> 6);
    int j = t & 63;
    float x = trainfeature[(size_t)row * ND + j];
    float ss = x * x;
    #pragma unroll
    for (int o = 32; o > 0; o >>= 1) ss += __shfl_xor(ss, o);
    float nrm = sqrtf(ss) + 1e-8f;
    tfn[(size_t)row * 64 + j] = x / nrm;
  } else if (blk < 4096) {               // wsum: 2 rows per block
    int b = (blk - 2048) * 2 + (t >> 7);
    int k = t & 127;
    float s = 0.f;
    #pragma unroll
    for (int tt = 0; tt < TOPK; ++tt)
      s += para[tt] * bsnf[((size_t)b * TOPK + tt) * ND + k];
    wsum[(size_t)b * ND + k] = s * (1.0f / TOPK);
  } else if (blk == 4096) {
    if (t == 0) {
      float s = 0.f;
      for (int tt = 0; tt < TOPK; ++tt) s += para[tt];
      *meanpara = s * (1.0f / TOPK);
    }
  } else if (blk < 4109) {               // lin_W pack: blk 4097..4108 -> kt 0..11
    int kt = blk - 4097;
    #pragma unroll
    for (int q = 0; q < 16; ++q) {
      int e = t * 16 + q;
      int nt = e >> 9, lane = (e >> 3) & 63, j = e & 7;
      float v = lin_W[(size_t)(kt * 32 + (lane >> 4) * 8 + j) * 128 + nt * 16 + (lane & 15)];
      linWp[(size_t)kt * 4096 + e] = f2bf(v);
    }
  } else if (blk < 4121) {               // qkv W pack: blk 4109..4120
    int id = blk - 4109;                 // 0..11
    int m = id >> 2, kt = id & 3;
    const float* Wm = m == 0 ? Wq : (m == 1 ? Wk : Wv);
    #pragma unroll
    for (int q = 0; q < 16; ++q) {
      int e = t * 16 + q;
      int nf = e >> 9, lane = (e >> 3) & 63, j = e & 7;
      float v = Wm[(size_t)(kt * 32 + (lane >> 4) * 8 + j) * 128 + nf * 16 + (lane & 15)];
      qkvWp[(size_t)((kt * 24 + m * 8 + nf) << 9) + (e & 511)] = f2bf(v);
    }
  } else {                               // translate_W pack: blk 4121..4124 -> kt 0..3
    int kt = blk - 4121;
    #pragma unroll
    for (int q = 0; q < 16; ++q) {
      int e = t * 16 + q;
      int nf = e >> 9, lane = (e >> 3) & 63, j = e & 7;
      float v = translate_W[(size_t)(kt * 32 + (lane >> 4) * 8 + j) * 128 + nf * 16 + (lane & 15)];
      twP[(size_t)((kt * 8 + nf) << 9) + (e & 511)] = f2bf(v);
    }
  }
}

// ---------------- generic f32 GEMM body (used by proj2 only) ----------------
__device__ __forceinline__ void gemm128_body(
    const float* __restrict__ A, const float* __restrict__ W,
    float* __restrict__ Cf, short* __restrict__ Xpack, int row0) {
  __shared__ float Ws[128][132];
  __shared__ float As[64][128];
  int t = threadIdx.x;
  for (int i = t; i < 128 * 32; i += 256) {
    int r = i >> 5, c = (i & 31) * 4;
    *(f4*)&Ws[r][c] = *(const f4*)&W[(size_t)r * 128 + c];
  }
  for (int i = t; i < 64 * 32; i += 256) {
    int r = i >> 5, c = (i & 31) * 4;
    *(f4*)&As[r][c] = *(const f4*)&A[(size_t)(row0 + r) * 128 + c];
  }
  __syncthreads();
  int tr = (t >> 5) * 8;
  int tc = (t & 31) * 4;
  float acc[8][4];
  #pragma unroll
  for (int i = 0; i < 8; i++)
    #pragma unroll
    for (int j = 0; j < 4; j++) acc[i][j] = 0.f;
  for (int k = 0; k < 128; k++) {
    f4 w = *(const f4*)&Ws[k][tc];
    #pragma unroll
    for (int i = 0; i < 8; i++) {
      float a = As[tr + i][k];
      acc[i][0] = fmaf(a, w[0], acc[i][0]);
      acc[i][1] = fmaf(a, w[1], acc[i][1]);
      acc[i][2] = fmaf(a, w[2], acc[i][2]);
      acc[i][3] = fmaf(a, w[3], acc[i][3]);
    }
  }
  if (Cf) {
    #pragma unroll
    for (int i = 0; i < 8; i++) {
      int r = row0 + tr + i;
      #pragma unroll
      for (int j = 0; j < 4; j++) Cf[(size_t)r * 128 + tc + j] = acc[i][j];
    }
  }
  if (Xpack) {
    int kb = row0 + tr;              // multiple of 8
    int kt = kb >> 5;
    int lane_hi = (kb >> 3) & 3;
    #pragma unroll
    for (int j = 0; j < 4; j++) {
      int n = tc + j;
      int ln = (n & 15) | (lane_hi << 4);
      bfrag h;
      #pragma unroll
      for (int i = 0; i < 8; i++) h[i] = f2bf(acc[i][j]);
      *(bfrag*)&Xpack[((size_t)(kt * 8 + (n >> 4)) * 64 + ln) * 8] = h;
    }
  }
}

// 2 projections in one launch, writing MFMA-packed bf16
__global__ __launch_bounds__(256) void proj2_kernel(
    const float* __restrict__ A0, const float* __restrict__ W0, short* __restrict__ T0,
    const float* __restrict__ A1, const float* __restrict__ W1, short* __restrict__ T1) {
  if (blockIdx.y == 0)
    gemm128_body(A0, W0, nullptr, T0, blockIdx.x * 64);
  else
    gemm128_body(A1, W1, nullptr, T1, blockIdx.x * 64);
}

// ---------------- big GEMM (R10 structure, PER-INSTRUCTION-CONTIGUOUS staging):
//  bx < 512  : E-tile = relu(graph @ XEP + gcnE_b) -> fused QKV -> bf16 Q/K/V
//  512..767  : emb_gb = relu(adj[bni[p]] @ XgP + gcn_b) (f32)
//  768..831  : simi = wsum @ translate_W + meanpara*translate_b
// Each wave owns 4 rows; one staging instruction = 64 lanes x 16B = one
// contiguous 1KB burst (16 full cache lines) from ONE row. Previous rounds'
// staging scattered each instruction over 64 lines x 16B (4 rows x 16 lines).
__global__ __launch_bounds__(256, 8) void big_gemm_kernel(
    const float* __restrict__ adj, const float* __restrict__ graphm,
    const short* __restrict__ XgP, const short* __restrict__ XEP,
    const int* __restrict__ bni,
    const float* __restrict__ gcnE_b, const float* __restrict__ gcn_b,
    const short* __restrict__ qkvWp,
    const float* __restrict__ wsum, const short* __restrict__ twP,
    const float* __restrict__ translate_b, const float* __restrict__ meanpara,
    float* __restrict__ emb_gb, short* __restrict__ Qa_bf,
    short* __restrict__ Ka_bf, short* __restrict__ Va_bf,
    float* __restrict__ simi) {
  const int bx0 = blockIdx.x;
  const int t = threadIdx.x;
  const int lane = t & 63;
  const int w = t >> 6;
  const int fr = lane & 15;
  const int kq = lane >> 4;

  if (bx0 >= 768) {                     // ---- simi blocks (fill stall bubbles)
    const int m0 = (bx0 - 768) * 64 + w * 16;
    const float mp = *meanpara;
    f4 acc[8];
    #pragma unroll
    for (int i = 0; i < 8; i++) acc[i] = (f4){0.f, 0.f, 0.f, 0.f};
    #pragma unroll
    for (int kt = 0; kt < 4; ++kt) {
      const float* ap = wsum + (size_t)(m0 + fr) * 128 + kt * 32 + kq * 8;
      bfrag a;
      #pragma unroll
      for (int j = 0; j < 8; ++j) a[j] = f2bf(ap[j]);
      #pragma unroll
      for (int nt = 0; nt < 8; ++nt) {
        bfrag bb = *(const bfrag*)&twP[(size_t)((kt * 8 + nt) << 9) + lane * 8];
        acc[nt] = __builtin_amdgcn_mfma_f32_16x16x32_bf16(a, bb, acc[nt], 0, 0, 0);
      }
    }
    #pragma unroll
    for (int nt = 0; nt < 8; ++nt) {
      int n = nt * 16 + fr;
      float bv = translate_b[n] * mp;
      #pragma unroll
      for (int r = 0; r < 4; ++r)
        simi[(size_t)(m0 + kq * 4 + r) * 128 + n] = acc[nt][r] + bv;
    }
    return;
  }

  const int bx = (bx0 & 7) * 96 + (bx0 >> 3);   // XCD swizzle (768 = 8*96)
  const bool isG = bx >= 512;
  const float* __restrict__ Am = isG ? adj : graphm;
  const short* __restrict__ Xp = isG ? XgP : XEP;
  const int m0 = (isG ? bx - 512 : bx) * BM;

  // each wave owns rows w*4..w*4+3; per-row pointer at lane*16B
  const float* rp[4];
  #pragma unroll
  for (int i = 0; i < 4; ++i) {
    int gr = m0 + w * 4 + i;
    if (isG) gr = bni[gr];
    rp[i] = Am + (size_t)gr * NN + lane * 4;
  }

  __shared__ short Abuf[2][BM * BKC];    // 2 x 8KB bf16, XOR-swizzled 16B units

  const short* Xb = Xp + (size_t)lane * 8;

  f4 acc0 = {0.f, 0.f, 0.f, 0.f}, acc1 = {0.f, 0.f, 0.f, 0.f};
  f4 st[4];
  #pragma unroll
  for (int i = 0; i < 4; i++) st[i] = *(const f4*)(rp[i]);

  for (int ms = 0; ms < NMS; ++ms) {
    const int cur = ms & 1;
    // convert + swizzled s4 writes; logical k-unit v = lane>>1, half = lane&1,
    // physical unit = v ^ (r&7)  (read side uses the same mapping)
    {
      #pragma unroll
      for (int i = 0; i < 4; ++i) {
        int r = w * 4 + i;
        s4 h;
        h[0] = f2bf(st[i][0]); h[1] = f2bf(st[i][1]);
        h[2] = f2bf(st[i][2]); h[3] = f2bf(st[i][3]);
        int u_sw = (lane >> 1) ^ (r & 7);
        *(s4*)&Abuf[cur][r * 256 + u_sw * 8 + (lane & 1) * 4] = h;
      }
    }
    __syncthreads();
    if (ms + 1 < NMS) {
      const int o = (ms + 1) * BKC;
      #pragma unroll
      for (int i = 0; i < 4; i++) st[i] = *(const f4*)(rp[i] + o);
    }
    // compute 8 k-steps on Abuf[cur]
    #pragma unroll
    for (int ks = 0; ks < 8; ++ks) {
      int u_sw = (ks * 4 + kq) ^ (fr & 7);
      bfrag a = *(const bfrag*)&Abuf[cur][fr * BKC + u_sw * 8];
      const short* xq = Xb + (size_t)(ms * 8 + ks) * 4096;
      bfrag b0 = *(const bfrag*)(xq + (2 * w) * 512);
      bfrag b1 = *(const bfrag*)(xq + (2 * w + 1) * 512);
      acc0 = __builtin_amdgcn_mfma_f32_16x16x32_bf16(a, b0, acc0, 0, 0, 0);
      acc1 = __builtin_amdgcn_mfma_f32_16x16x32_bf16(a, b1, acc1, 0, 0, 0);
    }
  }

  const int n0 = 2 * w * 16 + fr;
  if (isG) {
    // epilogue: bias + relu -> emb_gb (f32)
    const int orow = (bx - 512) * BM + kq * 4;
    #pragma unroll
    for (int r = 0; r < 4; ++r) {
      float v0 = fmaxf(acc0[r] + gcn_b[n0], 0.f);
      float v1 = fmaxf(acc1[r] + gcn_b[n0 + 16], 0.f);
      emb_gb[(size_t)(orow + r) * 128 + n0] = v0;
      emb_gb[(size_t)(orow + r) * 128 + n0 + 16] = v1;
    }
  } else {
    // epilogue: relu E-tile into LDS (bf16, padded rows of 136 shorts)
    short* Et = &Abuf[0][0];            // 16*136*2 = 4352 B, reuse Abuf
    #pragma unroll
    for (int r = 0; r < 4; ++r) {
      int rl = kq * 4 + r;
      Et[rl * 136 + n0] = f2bf(fmaxf(acc0[r] + gcnE_b[n0], 0.f));
      Et[rl * 136 + n0 + 16] = f2bf(fmaxf(acc1[r] + gcnE_b[n0 + 16], 0.f));
    }
    __syncthreads();
    // QKV: [16 rows][128] @ 128x384 (packed bf16 Wq|Wk|Wv)
    bfrag af[4];
    #pragma unroll
    for (int kt = 0; kt < 4; ++kt)
      af[kt] = *(const bfrag*)&Et[fr * 136 + kt * 32 + kq * 8];
    f4 qacc[6];
    #pragma unroll
    for (int i = 0; i < 6; ++i) qacc[i] = (f4){0.f, 0.f, 0.f, 0.f};
    #pragma unroll
    for (int kt = 0; kt < 4; ++kt) {
      #pragma unroll
      for (int i = 0; i < 6; ++i) {
        int nfg = w * 6 + i;
        bfrag bb = *(const bfrag*)&qkvWp[((size_t)(kt * 24 + nfg) << 9) + lane * 8];
        qacc[i] = __builtin_amdgcn_mfma_f32_16x16x32_bf16(af[kt], bb, qacc[i], 0, 0, 0);
      }
    }
    #pragma unroll
    for (int i = 0; i < 6; ++i) {
      int nfg = w * 6 + i;
      int m = nfg >> 3, nf = nfg & 7;
      short* dst = m == 0 ? Qa_bf : (m == 1 ? Ka_bf : Va_bf);
      int col = nf * 16 + fr;
      #pragma unroll
      for (int r = 0; r < 4; ++r)
        dst[(size_t)(m0 + kq * 4 + r) * 128 + col] = f2bf(qacc[i][r]);
    }
  }
}

// ---------------- fused attention: writes femb (bf16 [BSZ][384]) ----------------
__global__ __launch_bounds__(128) void attn_kernel(
    const int* __restrict__ node_rd,
    const short* __restrict__ Qa_bf, const short* __restrict__ Ka_bf,
    const short* __restrict__ Va_bf, const float* __restrict__ tfn,
    const float* __restrict__ emb_gb, const float* __restrict__ simi,
    short* __restrict__ femb_bf) {
  int b = blockIdx.x;
  int t = threadIdx.x;
  __shared__ int idx[CTX1];
  __shared__ float tf0[64];
  __shared__ float qv[128];
  __shared__ float cosv[CTX1];
  __shared__ float sc[8][CTX1];

  if (t < CTX1) idx[t] = node_rd[(size_t)b * CTX1 + t] + (t == 0 ? SRC : 0);
  __syncthreads();
  int i0 = idx[0];
  if (t < 64) tf0[t] = tfn[(size_t)i0 * 64 + t];
  qv[t] = bf2f(Qa_bf[(size_t)i0 * 128 + t]);
  __syncthreads();

  {  // cos[c]: 4 lanes per context
    int c = t >> 2, q = t & 3;
    const float* tfc = tfn + (size_t)idx[c] * 64;
    float s = 0.f;
    #pragma unroll
    for (int j = 0; j < 16; j++) s += tf0[q + j * 4] * tfc[q + j * 4];
    s += __shfl_xor(s, 1);
    s += __shfl_xor(s, 2);
    if (q == 0) cosv[c] = s;
  }
  __syncthreads();

  // scores[h][c], vectorized bf16 K loads
  for (int p = t; p < 256; p += 128) {
    int h = p >> 5, c = p & 31;
    const short* kp = Ka_bf + (size_t)idx[c] * 128 + h * 16;
    bfrag k0 = *(const bfrag*)(kp);
    bfrag k1 = *(const bfrag*)(kp + 8);
    float s = 0.f;
    #pragma unroll
    for (int j = 0; j < 8; j++) s += qv[h * 16 + j] * bf2f(k0[j]);
    #pragma unroll
    for (int j = 0; j < 8; j++) s += qv[h * 16 + 8 + j] * bf2f(k1[j]);
    sc[h][c] = s * 0.25f + cosv[c];
  }
  __syncthreads();

  {  // softmax over c, 16 lanes per head
    int h = t >> 4, l = t & 15;
    float s0 = sc[h][l], s1 = sc[h][l + 16];
    float m = fmaxf(s0, s1);
    #pragma unroll
    for (int o = 1; o < 16; o <<= 1) m = fmaxf(m, __shfl_xor(m, o));
    float e0 = expf(s0 - m), e1 = expf(s1 - m);
    float sum = e0 + e1;
    #pragma unroll
    for (int o = 1; o < 16; o <<= 1) sum += __shfl_xor(sum, o);
    float inv = 1.0f / sum;
    sc[h][l] = e0 * inv;
    sc[h][l + 16] = e1 * inv;
  }
  __syncthreads();

  {  // PV + elu -> femb[128..256)
    int h = t >> 4, d = t & 15;
    float o = 0.f;
    #pragma unroll 4
    for (int c = 0; c < CTX1; c++)
      o += sc[h][c] * bf2f(Va_bf[(size_t)idx[c] * 128 + h * 16 + d]);
    float e = (o > 0.f) ? o : expm1f(o);
    femb_bf[(size_t)b * 384 + 128 + t] = f2bf(e);
  }
  femb_bf[(size_t)b * 384 + t] = f2bf(emb_gb[(size_t)b * 128 + t]);
  femb_bf[(size_t)b * 384 + 256 + t] = f2bf(simi[(size_t)b * 128 + t]);
}

// ---------------- final projection: result = femb(bf16) @ lin_W + lin_b ----
__global__ __launch_bounds__(64) void final_kernel(
    const short* __restrict__ femb_bf, const short* __restrict__ linWp,
    const float* __restrict__ lin_b, float* __restrict__ outr) {
  const int m0 = blockIdx.x * 16;
  const int lane = threadIdx.x;
  const int fr = lane & 15;
  const int kq = lane >> 4;
  f4 acc[8];
  #pragma unroll
  for (int i = 0; i < 8; i++) acc[i] = (f4){0.f, 0.f, 0.f, 0.f};
  #pragma unroll
  for (int kt = 0; kt < 12; ++kt) {
    bfrag a = *(const bfrag*)&femb_bf[(size_t)(m0 + fr) * 384 + kt * 32 + kq * 8];
    #pragma unroll
    for (int nt = 0; nt < 8; ++nt) {
      bfrag bb = *(const bfrag*)&linWp[(size_t)(kt * 8 + nt) * 512 + lane * 8];
      acc[nt] = __builtin_amdgcn_mfma_f32_16x16x32_bf16(a, bb, acc[nt], 0, 0, 0);
    }
  }
  #pragma unroll
  for (int nt = 0; nt < 8; ++nt) {
    int n = nt * 16 + fr;
    float bv = lin_b[n];
    #pragma unroll
    for (int r = 0; r < 4; ++r)
      outr[(size_t)(m0 + kq * 4 + r) * 128 + n] = acc[nt][r] + bv;
  }
}

// ---------------- loss ----------------
__global__ __launch_bounds__(1024) void loss_kernel(
    const float* __restrict__ target, const float* __restrict__ result,
    float* __restrict__ out_loss) {
  int t = threadIdx.x;
  float s = 0.f;
  for (int b = t; b < BSZ; b += 1024) {
    float d = target[(size_t)b * 128 + DROPC] - result[(size_t)b * 128 + DROPC];
    s += d * d;
  }
  #pragma unroll
  for (int o = 32; o > 0; o >>= 1) s += __shfl_xor(s, o);
  __shared__ float red[16];
  if ((t & 63) == 0) red[t >> 6] = s;
  __syncthreads();
  if (t == 0) {
    float tot = 0.f;
    #pragma unroll
    for (int i = 0; i < 16; ++i) tot += red[i];
    out_loss[0] = tot * (1.0f / BSZ);
  }
}

extern "C" void kernel_launch(void* const* d_in, const int* in_sizes, int n_in,
                              void* d_out, int out_size, void* d_ws, size_t ws_size,
                              hipStream_t stream) {
  const float* adj = (const float*)d_in[0];
  const float* graphm = (const float*)d_in[1];
  const float* node_emb_gcn = (const float*)d_in[2];
  const float* trainfeature = (const float*)d_in[3];
  const float* target_emb = (const float*)d_in[4];
  const float* bsnf = (const float*)d_in[5];
  const int* batch_node_idx = (const int*)d_in[8];
  const int* node_rd = (const int*)d_in[9];
  const float* translate_W = (const float*)d_in[10];
  const float* translate_b = (const float*)d_in[11];
  const float* paraForCos = (const float*)d_in[12];
  const float* gcn_W = (const float*)d_in[13];
  const float* gcn_b = (const float*)d_in[14];
  const float* gcnE_W = (const float*)d_in[15];
  const float* gcnE_b = (const float*)d_in[16];
  const float* Wq = (const float*)d_in[17];
  const float* Wk = (const float*)d_in[18];
  const float* Wv = (const float*)d_in[19];
  const float* lin_W = (const float*)d_in[20];
  const float* lin_b = (const float*)d_in[21];

  char* ws = (char*)d_ws;
  size_t off = 0;
  auto alloc = [&](size_t bytes) {
    void* p = ws + off;
    off += (bytes + 255) & ~(size_t)255;
    return p;
  };
  short* XgP = (short*)alloc((size_t)128 * NN * 2);
  short* XEP = (short*)alloc((size_t)128 * NN * 2);
  float* tfn = (float*)alloc((size_t)NN * 64 * 4);
  float* wsum = (float*)alloc((size_t)BSZ * 128 * 4);
  float* simi = (float*)alloc((size_t)BSZ * 128 * 4);
  short* Qa_bf = (short*)alloc((size_t)NN * 128 * 2);
  short* Ka_bf = (short*)alloc((size_t)NN * 128 * 2);
  short* Va_bf = (short*)alloc((size_t)NN * 128 * 2);
  float* emb_gb = (float*)alloc((size_t)BSZ * 128 * 4);
  float* meanpara = (float*)alloc(256);
  short* femb_bf = (short*)alloc((size_t)BSZ * 384 * 2);
  short* linWp = (short*)alloc((size_t)12 * 4096 * 2);
  short* qkvWp = (short*)alloc((size_t)4 * 24 * 512 * 2);
  short* twP = (short*)alloc((size_t)4 * 8 * 512 * 2);

  float* out_res = (float*)d_out;
  float* out_loss = out_res + (size_t)BSZ * 128;

  prep_kernel<<<4125, 256, 0, stream>>>(trainfeature, bsnf, paraForCos, lin_W,
                                        Wq, Wk, Wv, translate_W,
                                        tfn, wsum, meanpara, linWp, qkvWp, twP);
  proj2_kernel<<<dim3(NN / 64, 2), 256, 0, stream>>>(node_emb_gcn, gcn_W, XgP,
                                                     trainfeature, gcnE_W, XEP);
  big_gemm_kernel<<<832, 256, 0, stream>>>(adj, graphm, XgP, XEP, batch_node_idx,
                                           gcnE_b, gcn_b, qkvWp, wsum, twP,
                                           translate_b, meanpara, emb_gb,
                                           Qa_bf, Ka_bf, Va_bf, simi);
  attn_kernel<<<BSZ, 128, 0, stream>>>(node_rd, Qa_bf, Ka_bf, Va_bf, tfn, emb_gb,
                                       simi, femb_bf);
  final_kernel<<<BSZ / 16, 64, 0, stream>>>(femb_bf, linWp, lin_b, out_res);
  loss_kernel<<<1, 1024, 0, stream>>>(target_emb, out_res, out_loss);
}

// Round 14
// 193.230 us; speedup vs baseline: 1.2528x; 1.2528x over previous
//
#include <hip/hip_runtime.h>
#include <hip/hip_bf16.h>

#define NN 8192
#define ND 128
#define BSZ 4096
#define CTX1 32
#define SRC 4096
#define TOPK 8
#define DROPC 5

#define BM 16          // rows per big_gemm block
#define BKC 256        // K floats per macro-step (1KB per row)
#define NMS (NN / BKC) // 32 macro-steps

using f4 = __attribute__((ext_vector_type(4))) float;
using bfrag = __attribute__((ext_vector_type(8))) short;

__device__ __forceinline__ short f2bf(float x) {
  __hip_bfloat16 h = __float2bfloat16(x);
  return __builtin_bit_cast(short, h);
}
__device__ __forceinline__ float bf2f(short s) {
  unsigned u = ((unsigned)(unsigned short)s) << 16;
  return __builtin_bit_cast(float, u);
}

// ---------------- prep: tfn, wsum, meanpara, lin_W / qkv / translate_W packs ----
__global__ __launch_bounds__(256) void prep_kernel(
    const float* __restrict__ trainfeature, const float* __restrict__ bsnf,
    const float* __restrict__ para, const float* __restrict__ lin_W,
    const float* __restrict__ Wq, const float* __restrict__ Wk,
    const float* __restrict__ Wv, const float* __restrict__ translate_W,
    float* __restrict__ tfn, float* __restrict__ wsum,
    float* __restrict__ meanpara, short* __restrict__ linWp,
    short* __restrict__ qkvWp, short* __restrict__ twP) {
  int blk = blockIdx.x;
  int t = threadIdx.x;
  if (blk < 2048) {                      // tfn: 4 rows per block, one wave per row
    int row = blk * 4 + (t >> 6);
    int j = t & 63;
    float x = trainfeature[(size_t)row * ND + j];
    float ss = x * x;
    #pragma unroll
    for (int o = 32; o > 0; o >>= 1) ss += __shfl_xor(ss, o);
    float nrm = sqrtf(ss) + 1e-8f;
    tfn[(size_t)row * 64 + j] = x / nrm;
  } else if (blk < 4096) {               // wsum: 2 rows per block
    int b = (blk - 2048) * 2 + (t >> 7);
    int k = t & 127;
    float s = 0.f;
    #pragma unroll
    for (int tt = 0; tt < TOPK; ++tt)
      s += para[tt] * bsnf[((size_t)b * TOPK + tt) * ND + k];
    wsum[(size_t)b * ND + k] = s * (1.0f / TOPK);
  } else if (blk == 4096) {
    if (t == 0) {
      float s = 0.f;
      for (int tt = 0; tt < TOPK; ++tt) s += para[tt];
      *meanpara = s * (1.0f / TOPK);
    }
  } else if (blk < 4109) {               // lin_W pack: blk 4097..4108 -> kt 0..11
    int kt = blk - 4097;
    #pragma unroll
    for (int q = 0; q < 16; ++q) {
      int e = t * 16 + q;
      int nt = e >> 9, lane = (e >> 3) & 63, j = e & 7;
      float v = lin_W[(size_t)(kt * 32 + (lane >> 4) * 8 + j) * 128 + nt * 16 + (lane & 15)];
      linWp[(size_t)kt * 4096 + e] = f2bf(v);
    }
  } else if (blk < 4121) {               // qkv W pack: blk 4109..4120
    int id = blk - 4109;                 // 0..11
    int m = id >> 2, kt = id & 3;
    const float* Wm = m == 0 ? Wq : (m == 1 ? Wk : Wv);
    #pragma unroll
    for (int q = 0; q < 16; ++q) {
      int e = t * 16 + q;
      int nf = e >> 9, lane = (e >> 3) & 63, j = e & 7;
      float v = Wm[(size_t)(kt * 32 + (lane >> 4) * 8 + j) * 128 + nf * 16 + (lane & 15)];
      qkvWp[(size_t)((kt * 24 + m * 8 + nf) << 9) + (e & 511)] = f2bf(v);
    }
  } else {                               // translate_W pack: blk 4121..4124 -> kt 0..3
    int kt = blk - 4121;
    #pragma unroll
    for (int q = 0; q < 16; ++q) {
      int e = t * 16 + q;
      int nf = e >> 9, lane = (e >> 3) & 63, j = e & 7;
      float v = translate_W[(size_t)(kt * 32 + (lane >> 4) * 8 + j) * 128 + nf * 16 + (lane & 15)];
      twP[(size_t)((kt * 8 + nf) << 9) + (e & 511)] = f2bf(v);
    }
  }
}

// ---------------- generic f32 GEMM body (used by proj2 only) ----------------
__device__ __forceinline__ void gemm128_body(
    const float* __restrict__ A, const float* __restrict__ W,
    float* __restrict__ Cf, short* __restrict__ Xpack, int row0) {
  __shared__ float Ws[128][132];
  __shared__ float As[64][128];
  int t = threadIdx.x;
  for (int i = t; i < 128 * 32; i += 256) {
    int r = i >> 5, c = (i & 31) * 4;
    *(f4*)&Ws[r][c] = *(const f4*)&W[(size_t)r * 128 + c];
  }
  for (int i = t; i < 64 * 32; i += 256) {
    int r = i >> 5, c = (i & 31) * 4;
    *(f4*)&As[r][c] = *(const f4*)&A[(size_t)(row0 + r) * 128 + c];
  }
  __syncthreads();
  int tr = (t >> 5) * 8;
  int tc = (t & 31) * 4;
  float acc[8][4];
  #pragma unroll
  for (int i = 0; i < 8; i++)
    #pragma unroll
    for (int j = 0; j < 4; j++) acc[i][j] = 0.f;
  for (int k = 0; k < 128; k++) {
    f4 w = *(const f4*)&Ws[k][tc];
    #pragma unroll
    for (int i = 0; i < 8; i++) {
      float a = As[tr + i][k];
      acc[i][0] = fmaf(a, w[0], acc[i][0]);
      acc[i][1] = fmaf(a, w[1], acc[i][1]);
      acc[i][2] = fmaf(a, w[2], acc[i][2]);
      acc[i][3] = fmaf(a, w[3], acc[i][3]);
    }
  }
  if (Cf) {
    #pragma unroll
    for (int i = 0; i < 8; i++) {
      int r = row0 + tr + i;
      #pragma unroll
      for (int j = 0; j < 4; j++) Cf[(size_t)r * 128 + tc + j] = acc[i][j];
    }
  }
  if (Xpack) {
    int kb = row0 + tr;              // multiple of 8
    int kt = kb >> 5;
    int lane_hi = (kb >> 3) & 3;
    #pragma unroll
    for (int j = 0; j < 4; j++) {
      int n = tc + j;
      int ln = (n & 15) | (lane_hi << 4);
      bfrag h;
      #pragma unroll
      for (int i = 0; i < 8; i++) h[i] = f2bf(acc[i][j]);
      *(bfrag*)&Xpack[((size_t)(kt * 8 + (n >> 4)) * 64 + ln) * 8] = h;
    }
  }
}

// 2 projections in one launch, writing MFMA-packed bf16
__global__ __launch_bounds__(256) void proj2_kernel(
    const float* __restrict__ A0, const float* __restrict__ W0, short* __restrict__ T0,
    const float* __restrict__ A1, const float* __restrict__ W1, short* __restrict__ T1) {
  if (blockIdx.y == 0)
    gemm128_body(A0, W0, nullptr, T0, blockIdx.x * 64);
  else
    gemm128_body(A1, W1, nullptr, T1, blockIdx.x * 64);
}

// ---------------- big GEMM (R10 empirical optimum) + simi fold:
//  bx < 512  : E-tile = relu(graph @ XEP + gcnE_b) -> fused QKV -> bf16 Q/K/V
//  512..767  : emb_gb = relu(adj[bni[p]] @ XgP + gcn_b) (f32)
//  768..831  : simi = wsum @ translate_W + meanpara*translate_b
__global__ __launch_bounds__(256, 8) void big_gemm_kernel(
    const float* __restrict__ adj, const float* __restrict__ graphm,
    const short* __restrict__ XgP, const short* __restrict__ XEP,
    const int* __restrict__ bni,
    const float* __restrict__ gcnE_b, const float* __restrict__ gcn_b,
    const short* __restrict__ qkvWp,
    const float* __restrict__ wsum, const short* __restrict__ twP,
    const float* __restrict__ translate_b, const float* __restrict__ meanpara,
    float* __restrict__ emb_gb, short* __restrict__ Qa_bf,
    short* __restrict__ Ka_bf, short* __restrict__ Va_bf,
    float* __restrict__ simi) {
  const int bx0 = blockIdx.x;
  const int t = threadIdx.x;
  const int lane = t & 63;
  const int w = t >> 6;
  const int fr = lane & 15;
  const int kq = lane >> 4;

  if (bx0 >= 768) {                     // ---- simi blocks (fill stall bubbles)
    const int m0 = (bx0 - 768) * 64 + w * 16;
    const float mp = *meanpara;
    f4 acc[8];
    #pragma unroll
    for (int i = 0; i < 8; i++) acc[i] = (f4){0.f, 0.f, 0.f, 0.f};
    #pragma unroll
    for (int kt = 0; kt < 4; ++kt) {
      const float* ap = wsum + (size_t)(m0 + fr) * 128 + kt * 32 + kq * 8;
      bfrag a;
      #pragma unroll
      for (int j = 0; j < 8; ++j) a[j] = f2bf(ap[j]);
      #pragma unroll
      for (int nt = 0; nt < 8; ++nt) {
        bfrag bb = *(const bfrag*)&twP[(size_t)((kt * 8 + nt) << 9) + lane * 8];
        acc[nt] = __builtin_amdgcn_mfma_f32_16x16x32_bf16(a, bb, acc[nt], 0, 0, 0);
      }
    }
    #pragma unroll
    for (int nt = 0; nt < 8; ++nt) {
      int n = nt * 16 + fr;
      float bv = translate_b[n] * mp;
      #pragma unroll
      for (int r = 0; r < 4; ++r)
        simi[(size_t)(m0 + kq * 4 + r) * 128 + n] = acc[nt][r] + bv;
    }
    return;
  }

  const int bx = (bx0 & 7) * 96 + (bx0 >> 3);   // XCD swizzle (768 = 8*96)
  const bool isG = bx >= 512;
  const float* __restrict__ Am = isG ? adj : graphm;
  const short* __restrict__ Xp = isG ? XgP : XEP;
  const int m0 = (isG ? bx - 512 : bx) * BM;

  // staging map: row sr = t>>4, 64B contiguous chunk ss = t&15
  const int sr = t >> 4;
  const int ss = t & 15;
  int grow = m0 + sr;
  if (isG) grow = bni[grow];
  const float* gsrc = Am + (size_t)grow * NN + ss * 16;

  __shared__ short Abuf[2][BM * BKC];    // 2 x 8KB bf16, XOR-swizzled 16B units

  const short* Xb = Xp + (size_t)lane * 8;

  f4 acc0 = {0.f, 0.f, 0.f, 0.f}, acc1 = {0.f, 0.f, 0.f, 0.f};
  f4 st[4];
  #pragma unroll
  for (int i = 0; i < 4; i++) st[i] = *(const f4*)(gsrc + i * 4);

  for (int ms = 0; ms < NMS; ++ms) {
    const int cur = ms & 1;
    // convert + swizzled ds_write (implicit vmcnt wait on st loads)
    {
      short* rb = &Abuf[cur][sr * BKC];
      #pragma unroll
      for (int j = 0; j < 2; ++j) {
        bfrag h;
        #pragma unroll
        for (int e = 0; e < 8; ++e) h[e] = f2bf(st[j * 2 + (e >> 2)][e & 3]);
        int u_sw = (ss * 2 + j) ^ (sr & 7);
        *(bfrag*)&rb[u_sw * 8] = h;
      }
    }
    __syncthreads();
    if (ms + 1 < NMS) {
      const float* g2 = gsrc + (size_t)(ms + 1) * BKC;
      #pragma unroll
      for (int i = 0; i < 4; i++) st[i] = *(const f4*)(g2 + i * 4);
    }
    // compute 8 k-steps on Abuf[cur]
    #pragma unroll
    for (int ks = 0; ks < 8; ++ks) {
      int u_sw = (ks * 4 + kq) ^ (fr & 7);
      bfrag a = *(const bfrag*)&Abuf[cur][fr * BKC + u_sw * 8];
      const short* xq = Xb + (size_t)(ms * 8 + ks) * 4096;
      bfrag b0 = *(const bfrag*)(xq + (2 * w) * 512);
      bfrag b1 = *(const bfrag*)(xq + (2 * w + 1) * 512);
      acc0 = __builtin_amdgcn_mfma_f32_16x16x32_bf16(a, b0, acc0, 0, 0, 0);
      acc1 = __builtin_amdgcn_mfma_f32_16x16x32_bf16(a, b1, acc1, 0, 0, 0);
    }
  }

  const int n0 = 2 * w * 16 + fr;
  if (isG) {
    // epilogue: bias + relu -> emb_gb (f32)
    const int orow = (bx - 512) * BM + kq * 4;
    #pragma unroll
    for (int r = 0; r < 4; ++r) {
      float v0 = fmaxf(acc0[r] + gcn_b[n0], 0.f);
      float v1 = fmaxf(acc1[r] + gcn_b[n0 + 16], 0.f);
      emb_gb[(size_t)(orow + r) * 128 + n0] = v0;
      emb_gb[(size_t)(orow + r) * 128 + n0 + 16] = v1;
    }
  } else {
    // epilogue: relu E-tile into LDS (bf16, padded rows of 136 shorts)
    short* Et = &Abuf[0][0];            // 16*136*2 = 4352 B, reuse Abuf
    #pragma unroll
    for (int r = 0; r < 4; ++r) {
      int rl = kq * 4 + r;
      Et[rl * 136 + n0] = f2bf(fmaxf(acc0[r] + gcnE_b[n0], 0.f));
      Et[rl * 136 + n0 + 16] = f2bf(fmaxf(acc1[r] + gcnE_b[n0 + 16], 0.f));
    }
    __syncthreads();
    // QKV: [16 rows][128] @ 128x384 (packed bf16 Wq|Wk|Wv)
    bfrag af[4];
    #pragma unroll
    for (int kt = 0; kt < 4; ++kt)
      af[kt] = *(const bfrag*)&Et[fr * 136 + kt * 32 + kq * 8];
    f4 qacc[6];
    #pragma unroll
    for (int i = 0; i < 6; ++i) qacc[i] = (f4){0.f, 0.f, 0.f, 0.f};
    #pragma unroll
    for (int kt = 0; kt < 4; ++kt) {
      #pragma unroll
      for (int i = 0; i < 6; ++i) {
        int nfg = w * 6 + i;
        bfrag bb = *(const bfrag*)&qkvWp[((size_t)(kt * 24 + nfg) << 9) + lane * 8];
        qacc[i] = __builtin_amdgcn_mfma_f32_16x16x32_bf16(af[kt], bb, qacc[i], 0, 0, 0);
      }
    }
    #pragma unroll
    for (int i = 0; i < 6; ++i) {
      int nfg = w * 6 + i;
      int m = nfg >> 3, nf = nfg & 7;
      short* dst = m == 0 ? Qa_bf : (m == 1 ? Ka_bf : Va_bf);
      int col = nf * 16 + fr;
      #pragma unroll
      for (int r = 0; r < 4; ++r)
        dst[(size_t)(m0 + kq * 4 + r) * 128 + col] = f2bf(qacc[i][r]);
    }
  }
}

// ---------------- fused attention: writes femb (bf16 [BSZ][384]) ----------------
__global__ __launch_bounds__(128) void attn_kernel(
    const int* __restrict__ node_rd,
    const short* __restrict__ Qa_bf, const short* __restrict__ Ka_bf,
    const short* __restrict__ Va_bf, const float* __restrict__ tfn,
    const float* __restrict__ emb_gb, const float* __restrict__ simi,
    short* __restrict__ femb_bf) {
  int b = blockIdx.x;
  int t = threadIdx.x;
  __shared__ int idx[CTX1];
  __shared__ float tf0[64];
  __shared__ float qv[128];
  __shared__ float cosv[CTX1];
  __shared__ float sc[8][CTX1];

  if (t < CTX1) idx[t] = node_rd[(size_t)b * CTX1 + t] + (t == 0 ? SRC : 0);
  __syncthreads();
  int i0 = idx[0];
  if (t < 64) tf0[t] = tfn[(size_t)i0 * 64 + t];
  qv[t] = bf2f(Qa_bf[(size_t)i0 * 128 + t]);
  __syncthreads();

  {  // cos[c]: 4 lanes per context
    int c = t >> 2, q = t & 3;
    const float* tfc = tfn + (size_t)idx[c] * 64;
    float s = 0.f;
    #pragma unroll
    for (int j = 0; j < 16; j++) s += tf0[q + j * 4] * tfc[q + j * 4];
    s += __shfl_xor(s, 1);
    s += __shfl_xor(s, 2);
    if (q == 0) cosv[c] = s;
  }
  __syncthreads();

  // scores[h][c], vectorized bf16 K loads
  for (int p = t; p < 256; p += 128) {
    int h = p >> 5, c = p & 31;
    const short* kp = Ka_bf + (size_t)idx[c] * 128 + h * 16;
    bfrag k0 = *(const bfrag*)(kp);
    bfrag k1 = *(const bfrag*)(kp + 8);
    float s = 0.f;
    #pragma unroll
    for (int j = 0; j < 8; j++) s += qv[h * 16 + j] * bf2f(k0[j]);
    #pragma unroll
    for (int j = 0; j < 8; j++) s += qv[h * 16 + 8 + j] * bf2f(k1[j]);
    sc[h][c] = s * 0.25f + cosv[c];
  }
  __syncthreads();

  {  // softmax over c, 16 lanes per head
    int h = t >> 4, l = t & 15;
    float s0 = sc[h][l], s1 = sc[h][l + 16];
    float m = fmaxf(s0, s1);
    #pragma unroll
    for (int o = 1; o < 16; o <<= 1) m = fmaxf(m, __shfl_xor(m, o));
    float e0 = expf(s0 - m), e1 = expf(s1 - m);
    float sum = e0 + e1;
    #pragma unroll
    for (int o = 1; o < 16; o <<= 1) sum += __shfl_xor(sum, o);
    float inv = 1.0f / sum;
    sc[h][l] = e0 * inv;
    sc[h][l + 16] = e1 * inv;
  }
  __syncthreads();

  {  // PV + elu -> femb[128..256)
    int h = t >> 4, d = t & 15;
    float o = 0.f;
    #pragma unroll 4
    for (int c = 0; c < CTX1; c++)
      o += sc[h][c] * bf2f(Va_bf[(size_t)idx[c] * 128 + h * 16 + d]);
    float e = (o > 0.f) ? o : expm1f(o);
    femb_bf[(size_t)b * 384 + 128 + t] = f2bf(e);
  }
  femb_bf[(size_t)b * 384 + t] = f2bf(emb_gb[(size_t)b * 128 + t]);
  femb_bf[(size_t)b * 384 + 256 + t] = f2bf(simi[(size_t)b * 128 + t]);
}

// ---------------- final projection: result = femb(bf16) @ lin_W + lin_b ----
__global__ __launch_bounds__(64) void final_kernel(
    const short* __restrict__ femb_bf, const short* __restrict__ linWp,
    const float* __restrict__ lin_b, float* __restrict__ outr) {
  const int m0 = blockIdx.x * 16;
  const int lane = threadIdx.x;
  const int fr = lane & 15;
  const int kq = lane >> 4;
  f4 acc[8];
  #pragma unroll
  for (int i = 0; i < 8; i++) acc[i] = (f4){0.f, 0.f, 0.f, 0.f};
  #pragma unroll
  for (int kt = 0; kt < 12; ++kt) {
    bfrag a = *(const bfrag*)&femb_bf[(size_t)(m0 + fr) * 384 + kt * 32 + kq * 8];
    #pragma unroll
    for (int nt = 0; nt < 8; ++nt) {
      bfrag bb = *(const bfrag*)&linWp[(size_t)(kt * 8 + nt) * 512 + lane * 8];
      acc[nt] = __builtin_amdgcn_mfma_f32_16x16x32_bf16(a, bb, acc[nt], 0, 0, 0);
    }
  }
  #pragma unroll
  for (int nt = 0; nt < 8; ++nt) {
    int n = nt * 16 + fr;
    float bv = lin_b[n];
    #pragma unroll
    for (int r = 0; r < 4; ++r)
      outr[(size_t)(m0 + kq * 4 + r) * 128 + n] = acc[nt][r] + bv;
  }
}

// ---------------- loss ----------------
__global__ __launch_bounds__(1024) void loss_kernel(
    const float* __restrict__ target, const float* __restrict__ result,
    float* __restrict__ out_loss) {
  int t = threadIdx.x;
  float s = 0.f;
  for (int b = t; b < BSZ; b += 1024) {
    float d = target[(size_t)b * 128 + DROPC] - result[(size_t)b * 128 + DROPC];
    s += d * d;
  }
  #pragma unroll
  for (int o = 32; o > 0; o >>= 1) s += __shfl_xor(s, o);
  __shared__ float red[16];
  if ((t & 63) == 0) red[t >> 6] = s;
  __syncthreads();
  if (t == 0) {
    float tot = 0.f;
    #pragma unroll
    for (int i = 0; i < 16; ++i) tot += red[i];
    out_loss[0] = tot * (1.0f / BSZ);
  }
}

extern "C" void kernel_launch(void* const* d_in, const int* in_sizes, int n_in,
                              void* d_out, int out_size, void* d_ws, size_t ws_size,
                              hipStream_t stream) {
  const float* adj = (const float*)d_in[0];
  const float* graphm = (const float*)d_in[1];
  const float* node_emb_gcn = (const float*)d_in[2];
  const float* trainfeature = (const float*)d_in[3];
  const float* target_emb = (const float*)d_in[4];
  const float* bsnf = (const float*)d_in[5];
  const int* batch_node_idx = (const int*)d_in[8];
  const int* node_rd = (const int*)d_in[9];
  const float* translate_W = (const float*)d_in[10];
  const float* translate_b = (const float*)d_in[11];
  const float* paraForCos = (const float*)d_in[12];
  const float* gcn_W = (const float*)d_in[13];
  const float* gcn_b = (const float*)d_in[14];
  const float* gcnE_W = (const float*)d_in[15];
  const float* gcnE_b = (const float*)d_in[16];
  const float* Wq = (const float*)d_in[17];
  const float* Wk = (const float*)d_in[18];
  const float* Wv = (const float*)d_in[19];
  const float* lin_W = (const float*)d_in[20];
  const float* lin_b = (const float*)d_in[21];

  char* ws = (char*)d_ws;
  size_t off = 0;
  auto alloc = [&](size_t bytes) {
    void* p = ws + off;
    off += (bytes + 255) & ~(size_t)255;
    return p;
  };
  short* XgP = (short*)alloc((size_t)128 * NN * 2);
  short* XEP = (short*)alloc((size_t)128 * NN * 2);
  float* tfn = (float*)alloc((size_t)NN * 64 * 4);
  float* wsum = (float*)alloc((size_t)BSZ * 128 * 4);
  float* simi = (float*)alloc((size_t)BSZ * 128 * 4);
  short* Qa_bf = (short*)alloc((size_t)NN * 128 * 2);
  short* Ka_bf = (short*)alloc((size_t)NN * 128 * 2);
  short* Va_bf = (short*)alloc((size_t)NN * 128 * 2);
  float* emb_gb = (float*)alloc((size_t)BSZ * 128 * 4);
  float* meanpara = (float*)alloc(256);
  short* femb_bf = (short*)alloc((size_t)BSZ * 384 * 2);
  short* linWp = (short*)alloc((size_t)12 * 4096 * 2);
  short* qkvWp = (short*)alloc((size_t)4 * 24 * 512 * 2);
  short* twP = (short*)alloc((size_t)4 * 8 * 512 * 2);

  float* out_res = (float*)d_out;
  float* out_loss = out_res + (size_t)BSZ * 128;

  prep_kernel<<<4125, 256, 0, stream>>>(trainfeature, bsnf, paraForCos, lin_W,
                                        Wq, Wk, Wv, translate_W,
                                        tfn, wsum, meanpara, linWp, qkvWp, twP);
  proj2_kernel<<<dim3(NN / 64, 2), 256, 0, stream>>>(node_emb_gcn, gcn_W, XgP,
                                                     trainfeature, gcnE_W, XEP);
  big_gemm_kernel<<<832, 256, 0, stream>>>(adj, graphm, XgP, XEP, batch_node_idx,
                                           gcnE_b, gcn_b, qkvWp, wsum, twP,
                                           translate_b, meanpara, emb_gb,
                                           Qa_bf, Ka_bf, Va_bf, simi);
  attn_kernel<<<BSZ, 128, 0, stream>>>(node_rd, Qa_bf, Ka_bf, Va_bf, tfn, emb_gb,
                                       simi, femb_bf);
  final_kernel<<<BSZ / 16, 64, 0, stream>>>(femb_bf, linWp, lin_b, out_res);
  loss_kernel<<<1, 1024, 0, stream>>>(target_emb, out_res, out_loss);
}